// Round 1
// baseline (242.647 us; speedup 1.0000x reference)
//
#include <hip/hip_runtime.h>
#include <hip/hip_bf16.h>

typedef __attribute__((ext_vector_type(4))) float f32x4;
typedef __attribute__((ext_vector_type(4))) float float4v;
typedef __attribute__((ext_vector_type(8))) short bf16x8;
typedef __attribute__((ext_vector_type(8))) unsigned short ushort8;

#define DEVI static __device__ __forceinline__

namespace {
constexpr int kB = 4, kL = 2048, kS = 2048, kH = 8, kE = 64, kD = 64;
constexpr int QB = 64;           // Q rows per block
constexpr int KVB = 64;          // KV positions per tile
constexpr int NKT = kS / KVB;    // 32
constexpr float kScale = 0.125f; // 1/sqrt(E)
constexpr float kEps = 1e-8f;
}

// XOR swizzle on flat byte offset for [rows][64] bf16 tiles (128B row stride):
// spreads 8 consecutive rows across 8 distinct 16B bank slots.
DEVI int swz(int byteoff) { return byteoff ^ (((byteoff >> 7) & 7) << 4); }

DEVI unsigned short f2bf(float f) {
  union { float f; unsigned u; } x; x.f = f;
  unsigned u = x.u;
  unsigned r = u + 0x7fffu + ((u >> 16) & 1u);  // RNE
  return (unsigned short)(r >> 16);
}

__global__ __launch_bounds__(256) void geo_attn_kernel(
    const float* __restrict__ Qg, const float* __restrict__ Kg,
    const float* __restrict__ Vg, float* __restrict__ Og) {
  __shared__ char qs[QB * 128];        // Q tile bf16 [l][e]
  __shared__ char ks[KVB * 128];       // K tile bf16 [s][e]
  __shared__ char vs[kD * 128];        // V tile bf16 TRANSPOSED [d][s]
  __shared__ char ps[4 * 16 * 128];    // per-wave P bf16 [16][64]
  __shared__ float qn2s[QB];
  __shared__ __align__(16) float kpart[KVB][4];

  const int t = (int)threadIdx.x;
  const int bh = (int)blockIdx.y;
  const int b = bh >> 3, h = bh & 7;
  const int l0 = (int)blockIdx.x * QB;

  const int wv = t >> 6;
  const int lane = t & 63;
  const int g = lane >> 4;
  const int cl = lane & 15;

  // ---- stage Q tile (QB x E) as bf16 + exact f32 qnorm2 partials ----
  {
    const int row = t >> 2;
    const int c0 = (t & 3) * 16;
    const float* qp = Qg + (((size_t)b * kL + (l0 + row)) * kH + h) * kE + c0;
    float pn = 0.f;
    __align__(16) unsigned short tmp[16];
#pragma unroll
    for (int i = 0; i < 4; ++i) {
      float4v v = *(const float4v*)(qp + 4 * i);
      pn += v.x * v.x + v.y * v.y + v.z * v.z + v.w * v.w;
      tmp[4*i+0] = f2bf(v.x); tmp[4*i+1] = f2bf(v.y);
      tmp[4*i+2] = f2bf(v.z); tmp[4*i+3] = f2bf(v.w);
    }
    *(ushort8*)(qs + swz(row * 128 + c0 * 2)) = *(const ushort8*)&tmp[0];
    *(ushort8*)(qs + swz(row * 128 + c0 * 2 + 16)) = *(const ushort8*)&tmp[8];
    kpart[row][t & 3] = pn;
  }
  __syncthreads();
  if (t < QB) qn2s[t] = kpart[t][0] + kpart[t][1] + kpart[t][2] + kpart[t][3];
  __syncthreads();

  // Q A-fragments: A[i][k], i = cl, k = g*8 + kk*32 + 0..7
  bf16x8 qa[2];
#pragma unroll
  for (int kk = 0; kk < 2; ++kk)
    qa[kk] = *(const bf16x8*)(qs + swz((16 * wv + cl) * 128 + (g * 8 + kk * 32) * 2));
  float qn2r[4];
#pragma unroll
  for (int r = 0; r < 4; ++r) qn2r[r] = qn2s[16 * wv + 4 * g + r];

  float m[4], lsum[4];
  f32x4 oacc[4];
#pragma unroll
  for (int r = 0; r < 4; ++r) { m[r] = -1e30f; lsum[r] = 0.f; }
#pragma unroll
  for (int dt = 0; dt < 4; ++dt) oacc[dt] = (f32x4){0.f, 0.f, 0.f, 0.f};

  for (int kt = 0; kt < NKT; ++kt) {
    __syncthreads();  // previous iteration's K/V reads complete
    // ---- stage K (bf16 + f32 knorm2 partials) and V (transposed bf16) ----
    {
      const int row = t >> 2;
      const int c0 = (t & 3) * 16;
      const size_t srow = ((size_t)b * kS + ((size_t)kt * KVB + row)) * kH + h;
      const float* kp = Kg + srow * kE + c0;
      float pn = 0.f;
      __align__(16) unsigned short tmp[16];
#pragma unroll
      for (int i = 0; i < 4; ++i) {
        float4v v = *(const float4v*)(kp + 4 * i);
        pn += v.x*v.x + v.y*v.y + v.z*v.z + v.w*v.w;
        tmp[4*i+0]=f2bf(v.x); tmp[4*i+1]=f2bf(v.y);
        tmp[4*i+2]=f2bf(v.z); tmp[4*i+3]=f2bf(v.w);
      }
      *(ushort8*)(ks + swz(row * 128 + c0 * 2)) = *(const ushort8*)&tmp[0];
      *(ushort8*)(ks + swz(row * 128 + c0 * 2 + 16)) = *(const ushort8*)&tmp[8];
      kpart[row][t & 3] = pn;
      const float* vp = Vg + srow * kD + c0;
#pragma unroll
      for (int i = 0; i < 4; ++i) {
        float4v v = *(const float4v*)(vp + 4 * i);
        *(unsigned short*)(vs + swz((c0 + 4*i + 0) * 128 + row * 2)) = f2bf(v.x);
        *(unsigned short*)(vs + swz((c0 + 4*i + 1) * 128 + row * 2)) = f2bf(v.y);
        *(unsigned short*)(vs + swz((c0 + 4*i + 2) * 128 + row * 2)) = f2bf(v.z);
        *(unsigned short*)(vs + swz((c0 + 4*i + 3) * 128 + row * 2)) = f2bf(v.w);
      }
    }
    __syncthreads();

    // ---- QK^T: dacc[nt][r] = dot(Q row 16wv+4g+r, K row 16nt+cl) ----
    f32x4 dacc[4];
#pragma unroll
    for (int nt = 0; nt < 4; ++nt) {
      f32x4 acc = {0.f, 0.f, 0.f, 0.f};
#pragma unroll
      for (int kk = 0; kk < 2; ++kk) {
        bf16x8 kb = *(const bf16x8*)(ks + swz((16 * nt + cl) * 128 + (g * 8 + kk * 32) * 2));
        acc = __builtin_amdgcn_mfma_f32_16x16x32_bf16(qa[kk], kb, acc, 0, 0, 0);
      }
      dacc[nt] = acc;
    }

    // ---- wedge scores + online softmax (rows live in 16-lane groups) ----
    float sc[4][4];
    float rmax[4] = {-1e30f, -1e30f, -1e30f, -1e30f};
#pragma unroll
    for (int nt = 0; nt < 4; ++nt) {
      float4v kp4 = *(const float4v*)&kpart[16 * nt + cl][0];
      float kn2 = kp4.x + kp4.y + kp4.z + kp4.w;
#pragma unroll
      for (int r = 0; r < 4; ++r) {
        float dot = dacc[nt][r];
        float w2 = qn2r[r] * kn2 - dot * dot;
        float s = sqrtf(fmaxf(w2, 0.f) + kEps) * kScale;
        sc[nt][r] = s;
        rmax[r] = fmaxf(rmax[r], s);
      }
    }
#pragma unroll
    for (int r = 0; r < 4; ++r) {
      float v = rmax[r];
      v = fmaxf(v, __shfl_xor(v, 1));
      v = fmaxf(v, __shfl_xor(v, 2));
      v = fmaxf(v, __shfl_xor(v, 4));
      v = fmaxf(v, __shfl_xor(v, 8));
      float mnew = fmaxf(m[r], v);
      float corr = __expf(m[r] - mnew);
      m[r] = mnew;
      lsum[r] *= corr;
#pragma unroll
      for (int dt = 0; dt < 4; ++dt) oacc[dt][r] *= corr;
      float psum = 0.f;
#pragma unroll
      for (int nt = 0; nt < 4; ++nt) {
        float p = __expf(sc[nt][r] - mnew);
        sc[nt][r] = p;
        psum += p;
      }
      psum += __shfl_xor(psum, 1);
      psum += __shfl_xor(psum, 2);
      psum += __shfl_xor(psum, 4);
      psum += __shfl_xor(psum, 8);
      lsum[r] += psum;
    }

    // ---- P -> per-wave LDS (bf16); same-wave RAW, no barrier needed ----
    const int pbase = wv * 2048;
#pragma unroll
    for (int nt = 0; nt < 4; ++nt)
#pragma unroll
      for (int r = 0; r < 4; ++r)
        *(unsigned short*)(ps + swz(pbase + (4 * g + r) * 128 + (16 * nt + cl) * 2)) =
            f2bf(sc[nt][r]);

    // ---- PV: oacc[dt] += P(16x64) * V(64x16dt) ----
    bf16x8 pa[2];
#pragma unroll
    for (int kk = 0; kk < 2; ++kk)
      pa[kk] = *(const bf16x8*)(ps + swz(pbase + cl * 128 + (g * 8 + kk * 32) * 2));
#pragma unroll
    for (int dt = 0; dt < 4; ++dt) {
      f32x4 acc = oacc[dt];
#pragma unroll
      for (int kk = 0; kk < 2; ++kk) {
        bf16x8 vb = *(const bf16x8*)(vs + swz((16 * dt + cl) * 128 + (g * 8 + kk * 32) * 2));
        acc = __builtin_amdgcn_mfma_f32_16x16x32_bf16(pa[kk], vb, acc, 0, 0, 0);
      }
      oacc[dt] = acc;
    }
  }

  // ---- epilogue: divide by lsum, store f32 ----
#pragma unroll
  for (int r = 0; r < 4; ++r) {
    const int l = l0 + 16 * wv + 4 * g + r;
    const float inv = 1.f / lsum[r];
    float* op = Og + (((size_t)b * kL + l) * kH + h) * kD;
#pragma unroll
    for (int dt = 0; dt < 4; ++dt)
      op[16 * dt + cl] = oacc[dt][r] * inv;
  }
}

extern "C" void kernel_launch(void* const* d_in, const int* in_sizes, int n_in,
                              void* d_out, int out_size, void* d_ws, size_t ws_size,
                              hipStream_t stream) {
  const float* Qg = (const float*)d_in[0];
  const float* Kg = (const float*)d_in[1];
  const float* Vg = (const float*)d_in[2];
  float* Og = (float*)d_out;
  dim3 grid(kL / QB, kB * kH);
  geo_attn_kernel<<<grid, dim3(256), 0, stream>>>(Qg, Kg, Vg, Og);
}

// Round 2
// 171.304 us; speedup vs baseline: 1.4165x; 1.4165x over previous
//
#include <hip/hip_runtime.h>

typedef __attribute__((ext_vector_type(4))) float f32x4;
typedef __attribute__((ext_vector_type(4))) float float4v;
typedef __attribute__((ext_vector_type(8))) short bf16x8;
typedef __attribute__((ext_vector_type(8))) unsigned short ushort8;

#define DEVI static __device__ __forceinline__

namespace {
constexpr int kB = 4, kL = 2048, kS = 2048, kH = 8;
constexpr int QB = 64;           // Q rows per block
constexpr int KVB = 64;          // KV positions per tile
constexpr int NKT = kS / KVB;    // 32
constexpr float kScaleLog2 = 0.125f * 1.44269504088896f;  // (1/sqrt(E)) * log2(e)
constexpr float kEps = 1e-8f;
}

// XOR swizzle on flat byte offset for [rows][64] bf16 tiles (128B row stride).
DEVI int swz(int byteoff) { return byteoff ^ (((byteoff >> 7) & 7) << 4); }

DEVI unsigned short f2bf(float f) {
  union { float f; unsigned u; } x; x.f = f;
  unsigned u = x.u;
  unsigned r = u + 0x7fffu + ((u >> 16) & 1u);  // RNE
  return (unsigned short)(r >> 16);
}

DEVI unsigned pack2(float a, float b) {
  return (unsigned)f2bf(a) | ((unsigned)f2bf(b) << 16);
}

// ---------- prepass 1: K [B,S,H,E] f32 -> Kb [B,H,S,E] bf16 + kn2 f32 ----------
__global__ __launch_bounds__(256) void prep_k(const float* __restrict__ Kg,
                                              unsigned short* __restrict__ Kb,
                                              float* __restrict__ kn2) {
  const int tid = (int)blockIdx.x * 256 + (int)threadIdx.x;
  const int r = tid >> 2, qd = tid & 3;   // input row, quarter
  const int b = r >> 14;                  // S*H = 16384 rows per b
  const int s = (r >> 3) & 2047;
  const int h = r & 7;
  const float* src = Kg + (size_t)r * 64 + qd * 16;
  float pn = 0.f;
  __align__(16) unsigned short tmp[16];
#pragma unroll
  for (int i = 0; i < 4; ++i) {
    float4v v = *(const float4v*)(src + 4 * i);
    pn += v.x * v.x + v.y * v.y + v.z * v.z + v.w * v.w;
    tmp[4*i+0] = f2bf(v.x); tmp[4*i+1] = f2bf(v.y);
    tmp[4*i+2] = f2bf(v.z); tmp[4*i+3] = f2bf(v.w);
  }
  const size_t orow = (size_t)(b * 8 + h) * 2048 + s;
  unsigned short* dst = Kb + orow * 64 + qd * 16;
  *(ushort8*)(dst) = *(const ushort8*)&tmp[0];
  *(ushort8*)(dst + 8) = *(const ushort8*)&tmp[8];
  pn += __shfl_xor(pn, 1);
  pn += __shfl_xor(pn, 2);
  if (qd == 0) kn2[orow] = pn;
}

// ---------- prepass 2: V [B,S,H,D] f32 -> Vt [B,H,D,S] bf16, sigma-permuted ----
// Within each 64-wide s-tile, output slot k holds V[s0 + sigma(k)][d] where
// sigma(k) = 16*(2*(k>>5) + ((k&7)>>2)) + 4*((k>>3)&3) + (k&3).
// The attention kernel applies the same sigma to P's registers (for free), so
// the PV contraction is unchanged while P stays entirely in registers.
__global__ __launch_bounds__(256) void prep_v(const float* __restrict__ Vg,
                                              unsigned short* __restrict__ Vt) {
  __shared__ char tile[64 * 128];  // [s][d] bf16, swizzled
  const int t = (int)threadIdx.x;
  const int bid = (int)blockIdx.x;
  const int st = bid & 31;  // s-tile
  const int bh = bid >> 5;
  const int b = bh >> 3, h = bh & 7;
  {
    const int sl = t >> 2, c0 = (t & 3) * 16;
    const float* src = Vg + (((size_t)b * 2048 + st * 64 + sl) * 8 + h) * 64 + c0;
    __align__(16) unsigned short tmp[16];
#pragma unroll
    for (int i = 0; i < 4; ++i) {
      float4v v = *(const float4v*)(src + 4 * i);
      tmp[4*i+0] = f2bf(v.x); tmp[4*i+1] = f2bf(v.y);
      tmp[4*i+2] = f2bf(v.z); tmp[4*i+3] = f2bf(v.w);
    }
    *(ushort8*)(tile + swz(sl * 128 + c0 * 2)) = *(const ushort8*)&tmp[0];
    *(ushort8*)(tile + swz(sl * 128 + c0 * 2 + 16)) = *(const ushort8*)&tmp[8];
  }
  __syncthreads();
  {
    const int d = t >> 2, k0 = (t & 3) * 16;
    __align__(16) unsigned short outv[16];
#pragma unroll
    for (int i = 0; i < 16; ++i) {
      const int k = k0 + i;
      const int gg = (k >> 3) & 3, kk = k >> 5, c = k & 7;
      const int sig = ((kk * 2 + (c >> 2)) << 4) | (gg << 2) | (c & 3);
      outv[i] = *(const unsigned short*)(tile + swz(sig * 128 + d * 2));
    }
    unsigned short* dst = Vt + ((size_t)(b * 8 + h) * 64 + d) * 2048 + st * 64 + k0;
    *(ushort8*)(dst) = *(const ushort8*)&outv[0];
    *(ushort8*)(dst + 8) = *(const ushort8*)&outv[8];
  }
}

// ---------- main attention kernel ----------
__global__ __launch_bounds__(256) void geo_attn_kernel(
    const float* __restrict__ Qg, const unsigned short* __restrict__ Kb,
    const unsigned short* __restrict__ Vt, const float* __restrict__ kn2g,
    float* __restrict__ Og) {
  __shared__ char qs[8192];         // Q tile bf16 [l][e], swizzled
  __shared__ char ks[2][8192];      // K tile bf16 [s][e], swizzled, dbuf
  __shared__ char vs[2][8192];      // V tile bf16 [d][k(sigma)], swizzled, dbuf
  __shared__ float qn2s[64];
  __shared__ __align__(16) float kpart[64][4];

  const int t = (int)threadIdx.x;
  const int bh = (int)blockIdx.y;
  const int l0 = (int)blockIdx.x * QB;
  const int wv = t >> 6, lane = t & 63, gg = lane >> 4, cl = lane & 15;

  // ---- stage Q tile as bf16 + exact f32 qnorm2 ----
  {
    const int row = t >> 2, c0 = (t & 3) * 16;
    const int b = bh >> 3, h = bh & 7;
    const float* qp = Qg + (((size_t)b * kL + (l0 + row)) * kH + h) * 64 + c0;
    float pn = 0.f;
    __align__(16) unsigned short tmp[16];
#pragma unroll
    for (int i = 0; i < 4; ++i) {
      float4v v = *(const float4v*)(qp + 4 * i);
      pn += v.x * v.x + v.y * v.y + v.z * v.z + v.w * v.w;
      tmp[4*i+0] = f2bf(v.x); tmp[4*i+1] = f2bf(v.y);
      tmp[4*i+2] = f2bf(v.z); tmp[4*i+3] = f2bf(v.w);
    }
    *(ushort8*)(qs + swz(row * 128 + c0 * 2)) = *(const ushort8*)&tmp[0];
    *(ushort8*)(qs + swz(row * 128 + c0 * 2 + 16)) = *(const ushort8*)&tmp[8];
    kpart[row][t & 3] = pn;
  }
  __syncthreads();
  if (t < 64) qn2s[t] = kpart[t][0] + kpart[t][1] + kpart[t][2] + kpart[t][3];

  // ---- staging addresses (bf16 straight copies; LDS dest pre-swizzled) ----
  const unsigned short* kt_base = Kb + (size_t)bh * (2048 * 64);
  const unsigned short* vt_base = Vt + (size_t)bh * (64 * 2048);
  const float* kn2t = kn2g + (size_t)bh * 2048;
  const int lin0 = t * 32, lin1 = lin0 + 16;
  const int dv0 = lin0 >> 7, cb0 = (lin0 & 127) >> 1;
  const int dv1 = lin1 >> 7, cb1 = (lin1 & 127) >> 1;
  const int sk0 = swz(lin0), sk1 = swz(lin1);

  ushort8 gk0, gk1, gv0, gv1;
  gk0 = *(const ushort8*)(kt_base + (lin0 >> 1));
  gk1 = *(const ushort8*)(kt_base + (lin1 >> 1));
  gv0 = *(const ushort8*)(vt_base + dv0 * 2048 + cb0);
  gv1 = *(const ushort8*)(vt_base + dv1 * 2048 + cb1);
  *(ushort8*)(ks[0] + sk0) = gk0; *(ushort8*)(ks[0] + sk1) = gk1;
  *(ushort8*)(vs[0] + sk0) = gv0; *(ushort8*)(vs[0] + sk1) = gv1;
  __syncthreads();

  // Q B-fragment (swapped-operand QK^T: B[k][j] = Q[16wv+j][k], j = cl)
  bf16x8 qb[2];
  qb[0] = *(const bf16x8*)(qs + swz((wv * 16 + cl) * 128 + gg * 16));
  qb[1] = *(const bf16x8*)(qs + swz((wv * 16 + cl) * 128 + gg * 16 + 64));
  const float qn2 = qn2s[wv * 16 + cl];

  float m = -1e30f, lsum = 0.f;
  f32x4 oacc[4];
#pragma unroll
  for (int dt = 0; dt < 4; ++dt) oacc[dt] = (f32x4){0.f, 0.f, 0.f, 0.f};

  int cur = 0;
  for (int kt = 0; kt < NKT; ++kt) {
    const bool hn = (kt + 1 < NKT);
    if (hn) {  // issue next-tile global loads early (latency hides under compute)
      const int kn = kt + 1;
      gk0 = *(const ushort8*)(kt_base + kn * 4096 + (lin0 >> 1));
      gk1 = *(const ushort8*)(kt_base + kn * 4096 + (lin1 >> 1));
      gv0 = *(const ushort8*)(vt_base + dv0 * 2048 + kn * 64 + cb0);
      gv1 = *(const ushort8*)(vt_base + dv1 * 2048 + kn * 64 + cb1);
    }
    const char* ksc = ks[cur];
    const char* vsc = vs[cur];

    float4v kn2v[4];
#pragma unroll
    for (int nt = 0; nt < 4; ++nt)
      kn2v[nt] = *(const float4v*)(kn2t + kt * 64 + nt * 16 + gg * 4);

    // ---- QK^T swapped: D[s_loc=4gg+r (per nt)][q=cl] ----
    f32x4 dacc[4];
#pragma unroll
    for (int nt = 0; nt < 4; ++nt) {
      bf16x8 ka0 = *(const bf16x8*)(ksc + swz((nt * 16 + cl) * 128 + gg * 16));
      bf16x8 ka1 = *(const bf16x8*)(ksc + swz((nt * 16 + cl) * 128 + gg * 16 + 64));
      f32x4 acc = {0.f, 0.f, 0.f, 0.f};
      acc = __builtin_amdgcn_mfma_f32_16x16x32_bf16(ka0, qb[0], acc, 0, 0, 0);
      acc = __builtin_amdgcn_mfma_f32_16x16x32_bf16(ka1, qb[1], acc, 0, 0, 0);
      dacc[nt] = acc;
    }

    // ---- wedge scores (log2 domain) + online softmax; lane owns q = 16wv+cl ----
    float sc[4][4];
    float rmax = -1e30f;
#pragma unroll
    for (int nt = 0; nt < 4; ++nt)
#pragma unroll
      for (int r = 0; r < 4; ++r) {
        const float dot = dacc[nt][r];
        const float w2 = fmaf(-dot, dot, qn2 * kn2v[nt][r]);
        const float s = sqrtf(fmaxf(w2, 0.f) + kEps) * kScaleLog2;
        sc[nt][r] = s;
        rmax = fmaxf(rmax, s);
      }
    rmax = fmaxf(rmax, __shfl_xor(rmax, 16));
    rmax = fmaxf(rmax, __shfl_xor(rmax, 32));
    const float mnew = fmaxf(m, rmax);
    const float corr = exp2f(m - mnew);
    m = mnew;
    lsum *= corr;
    float corr4[4];
#pragma unroll
    for (int r = 0; r < 4; ++r)
      corr4[r] = __shfl(corr, (lane & 48) | (gg * 4 + r));
#pragma unroll
    for (int dt = 0; dt < 4; ++dt)
#pragma unroll
      for (int r = 0; r < 4; ++r) oacc[dt][r] *= corr4[r];
    float psum = 0.f;
#pragma unroll
    for (int nt = 0; nt < 4; ++nt)
#pragma unroll
      for (int r = 0; r < 4; ++r) {
        const float p = exp2f(sc[nt][r] - mnew);
        sc[nt][r] = p;
        psum += p;
      }
    psum += __shfl_xor(psum, 16);
    psum += __shfl_xor(psum, 32);
    lsum += psum;

    // ---- P fragments: sigma makes them lane-local (zero shuffles/LDS) ----
    union { bf16x8 v; unsigned w[4]; } pa0, pa1;
    pa0.w[0] = pack2(sc[0][0], sc[0][1]); pa0.w[1] = pack2(sc[0][2], sc[0][3]);
    pa0.w[2] = pack2(sc[1][0], sc[1][1]); pa0.w[3] = pack2(sc[1][2], sc[1][3]);
    pa1.w[0] = pack2(sc[2][0], sc[2][1]); pa1.w[1] = pack2(sc[2][2], sc[2][3]);
    pa1.w[2] = pack2(sc[3][0], sc[3][1]); pa1.w[3] = pack2(sc[3][2], sc[3][3]);

    // ---- PV: oacc[dt] rows q=4gg+r, col d=16dt+cl ----
#pragma unroll
    for (int dt = 0; dt < 4; ++dt) {
      bf16x8 vb0 = *(const bf16x8*)(vsc + swz((dt * 16 + cl) * 128 + gg * 16));
      bf16x8 vb1 = *(const bf16x8*)(vsc + swz((dt * 16 + cl) * 128 + gg * 16 + 64));
      f32x4 acc = oacc[dt];
      acc = __builtin_amdgcn_mfma_f32_16x16x32_bf16(pa0.v, vb0, acc, 0, 0, 0);
      acc = __builtin_amdgcn_mfma_f32_16x16x32_bf16(pa1.v, vb1, acc, 0, 0, 0);
      oacc[dt] = acc;
    }

    if (hn) {  // T14: LDS writes after compute, just before the barrier
      char* ksn = ks[cur ^ 1]; char* vsn = vs[cur ^ 1];
      *(ushort8*)(ksn + sk0) = gk0; *(ushort8*)(ksn + sk1) = gk1;
      *(ushort8*)(vsn + sk0) = gv0; *(ushort8*)(vsn + sk1) = gv1;
    }
    __syncthreads();
    cur ^= 1;
  }

  // ---- epilogue ----
  const float inv = 1.f / lsum;
  float inv4[4];
#pragma unroll
  for (int r = 0; r < 4; ++r)
    inv4[r] = __shfl(inv, (lane & 48) | (gg * 4 + r));
  const int b = bh >> 3, h = bh & 7;
#pragma unroll
  for (int r = 0; r < 4; ++r) {
    const int l = l0 + wv * 16 + gg * 4 + r;
    float* op = Og + (((size_t)b * kL + l) * kH + h) * 64;
#pragma unroll
    for (int dt = 0; dt < 4; ++dt)
      op[dt * 16 + cl] = oacc[dt][r] * inv4[r];
  }
}

extern "C" void kernel_launch(void* const* d_in, const int* in_sizes, int n_in,
                              void* d_out, int out_size, void* d_ws, size_t ws_size,
                              hipStream_t stream) {
  const float* Qg = (const float*)d_in[0];
  const float* Kg = (const float*)d_in[1];
  const float* Vg = (const float*)d_in[2];
  float* Og = (float*)d_out;
  // workspace layout: Kb bf16 8MB | Vt bf16 8MB | kn2 f32 256KB  (16.25MB total)
  unsigned short* Kb = (unsigned short*)d_ws;
  unsigned short* Vt = (unsigned short*)((char*)d_ws + (8u << 20));
  float* kn2 = (float*)((char*)d_ws + (16u << 20));
  prep_k<<<1024, 256, 0, stream>>>(Kg, Kb, kn2);
  prep_v<<<1024, 256, 0, stream>>>(Vg, Vt);
  dim3 grid(kL / QB, kB * kH);
  geo_attn_kernel<<<grid, dim3(256), 0, stream>>>(Qg, Kb, Vt, kn2, Og);
}

// Round 3
// 83.961 us; speedup vs baseline: 2.8900x; 2.0403x over previous
//
#include <hip/hip_runtime.h>

typedef __attribute__((ext_vector_type(4))) float f32x4;
typedef __attribute__((ext_vector_type(4))) float float4v;
typedef __attribute__((ext_vector_type(8))) short bf16x8;
typedef __attribute__((ext_vector_type(8))) unsigned short ushort8;

#define DEVI static __device__ __forceinline__

namespace {
constexpr int kL = 2048, kS = 2048, kH = 8;
constexpr int QB = 64, KVB = 64, NKT = kS / KVB;
constexpr float kC = 0.18033688f;        // (1/8) * log2(e), folded into Q
constexpr float kEpsC = 3.252139e-10f;   // kC^2 * 1e-8
constexpr int KTILE = 8448;              // 8192 B data + 256 B kn2 tail
constexpr int VTILE = 8192;
constexpr int KBH = 32 * KTILE;
constexpr int VBH = 32 * VTILE;
}

// XOR swizzle on flat byte offset for [rows][64] bf16 tiles (128B row stride).
DEVI int swz(int byteoff) { return byteoff ^ (((byteoff >> 7) & 7) << 4); }

DEVI unsigned cvtpk(float lo, float hi) {
  unsigned r;
  asm("v_cvt_pk_bf16_f32 %0, %1, %2" : "=v"(r) : "v"(lo), "v"(hi));
  return r;
}

// ---------- prepass 1: K -> tiled, PRE-SWIZZLED bf16 tiles + kn2 tail ----------
// Tile t = bh*32+kt is 8448 B: 8192 B of bf16 such that a LINEAR copy into LDS
// matches the kernel's swizzled reads (LDS[y] = K[swz(y)]), then 64 f32 kn2.
__global__ __launch_bounds__(256) void prep_k(const float* __restrict__ Kg,
                                              char* __restrict__ Kb) {
  const int chunk = (int)blockIdx.x * 256 + (int)threadIdx.x;  // one 16B chunk
  const int tile = chunk >> 9;
  const int i = chunk & 511;
  const int bh = tile >> 5, kt = tile & 31;
  const int b = bh >> 3, h = bh & 7;
  const int row = i >> 3;
  const int colsel = (i & 7) ^ (row & 7);     // swz on chunk index
  const int s = kt * 64 + row;
  const float* src = Kg + (((size_t)b * kS + s) * kH + h) * 64 + colsel * 8;
  float4v v0 = *(const float4v*)(src);
  float4v v1 = *(const float4v*)(src + 4);
  float pn = v0.x*v0.x + v0.y*v0.y + v0.z*v0.z + v0.w*v0.w
           + v1.x*v1.x + v1.y*v1.y + v1.z*v1.z + v1.w*v1.w;
  union { unsigned w[4]; ushort8 u; } o;
  o.w[0] = cvtpk(v0.x, v0.y); o.w[1] = cvtpk(v0.z, v0.w);
  o.w[2] = cvtpk(v1.x, v1.y); o.w[3] = cvtpk(v1.z, v1.w);
  char* tb = Kb + (size_t)tile * KTILE;
  *(ushort8*)(tb + i * 16) = o.u;
  pn += __shfl_xor(pn, 1);
  pn += __shfl_xor(pn, 2);
  pn += __shfl_xor(pn, 4);
  if ((i & 7) == 0) *(float*)(tb + 8192 + row * 4) = pn;  // exact f32 |k|^2
}

// ---------- prepass 2: V -> tiled, sigma-permuted, PRE-SWIZZLED bf16 ----------
// Logical LDS layout: [d][k], where slot k holds V[s0 + sigma(k)][d]; sigma makes
// the attention kernel's P fragments lane-local. Stored pre-swizzled for
// linear global_load_lds staging.
__global__ __launch_bounds__(256) void prep_v(const float* __restrict__ Vg,
                                              char* __restrict__ Vt) {
  __shared__ char tile[64 * 128];  // [s][d] bf16, swizzled
  const int t = (int)threadIdx.x;
  const int bid = (int)blockIdx.x;
  const int st = bid & 31, bh = bid >> 5;
  const int b = bh >> 3, h = bh & 7;
  {
    const int sl = t >> 2, c0 = (t & 3) * 16;
    const float* src = Vg + (((size_t)b * kS + st * 64 + sl) * kH + h) * 64 + c0;
    float4v v0 = *(const float4v*)(src);
    float4v v1 = *(const float4v*)(src + 4);
    float4v v2 = *(const float4v*)(src + 8);
    float4v v3 = *(const float4v*)(src + 12);
    union { unsigned w[4]; ushort8 u; } t0, t1;
    t0.w[0] = cvtpk(v0.x, v0.y); t0.w[1] = cvtpk(v0.z, v0.w);
    t0.w[2] = cvtpk(v1.x, v1.y); t0.w[3] = cvtpk(v1.z, v1.w);
    t1.w[0] = cvtpk(v2.x, v2.y); t1.w[1] = cvtpk(v2.z, v2.w);
    t1.w[2] = cvtpk(v3.x, v3.y); t1.w[3] = cvtpk(v3.z, v3.w);
    *(ushort8*)(tile + swz(sl * 128 + c0 * 2)) = t0.u;
    *(ushort8*)(tile + swz(sl * 128 + c0 * 2 + 16)) = t1.u;
  }
  __syncthreads();
  char* dst = Vt + (size_t)bid * VTILE;
#pragma unroll
  for (int cc = 0; cc < 2; ++cc) {
    const int i = t * 2 + cc;
    const int z = swz(i * 16);
    const int d = z >> 7;
    const int k0 = ((z >> 4) & 7) * 8;
    union { unsigned short s[8]; ushort8 u; } o;
#pragma unroll
    for (int j = 0; j < 8; ++j) {
      const int k = k0 + j;
      const int sig = (((k >> 5) * 2 + ((k & 7) >> 2)) << 4) |
                      (((k >> 3) & 3) << 2) | (k & 3);
      o.s[j] = *(const unsigned short*)(tile + swz(sig * 128 + d * 2));
    }
    *(ushort8*)(dst + i * 16) = o.u;
  }
}

// ---------- main attention kernel ----------
__global__ __launch_bounds__(256) void geo_attn_kernel(
    const float* __restrict__ Qg, const char* __restrict__ Kb,
    const char* __restrict__ Vt, float* __restrict__ Og) {
  __shared__ char lds[2][16384];  // per buf: 8KB K tile | 8KB V tile (linear)

  const int t = (int)threadIdx.x;
  const int wv = t >> 6, lane = t & 63, gg = lane >> 4, cl = lane & 15;
  const int bh = (int)blockIdx.y, b = bh >> 3, h = bh & 7;
  const int l0 = (int)blockIdx.x * QB;

  // ---- Q fragment straight from global, scaled by kC; exact f32 |q|^2 ----
  const int q = l0 + wv * 16 + cl;
  const float* qp = Qg + (((size_t)b * kL + q) * kH + h) * 64;
  float4v x0 = *(const float4v*)(qp + gg * 8);
  float4v x1 = *(const float4v*)(qp + gg * 8 + 4);
  float4v x2 = *(const float4v*)(qp + gg * 8 + 32);
  float4v x3 = *(const float4v*)(qp + gg * 8 + 36);
  x0 *= kC; x1 *= kC; x2 *= kC; x3 *= kC;
  float pn = 0.f;
#pragma unroll
  for (int j = 0; j < 4; ++j) {
    pn = fmaf(x0[j], x0[j], pn); pn = fmaf(x1[j], x1[j], pn);
    pn = fmaf(x2[j], x2[j], pn); pn = fmaf(x3[j], x3[j], pn);
  }
  union frag { bf16x8 v; unsigned w[4]; };
  frag qb0, qb1;
  qb0.w[0] = cvtpk(x0.x, x0.y); qb0.w[1] = cvtpk(x0.z, x0.w);
  qb0.w[2] = cvtpk(x1.x, x1.y); qb0.w[3] = cvtpk(x1.z, x1.w);
  qb1.w[0] = cvtpk(x2.x, x2.y); qb1.w[1] = cvtpk(x2.z, x2.w);
  qb1.w[2] = cvtpk(x3.x, x3.y); qb1.w[3] = cvtpk(x3.z, x3.w);
  pn += __shfl_xor(pn, 16);
  pn += __shfl_xor(pn, 32);
  const float qn2 = pn;  // kC^2 * |q|^2 (full row)

  // ---- staging: wave wv owns 4KB of the 16KB {K,V} tile pair ----
  const char* gsrc0 = (wv < 2) ? (Kb + (size_t)bh * KBH) : (Vt + (size_t)bh * VBH);
  const int gstride = (wv < 2) ? KTILE : VTILE;
  const char* gp = gsrc0 + (wv & 1) * 4096 + lane * 16;
  const char* ktail = Kb + (size_t)bh * KBH + 8192;

#define STAGE(BUF) do { \
    char* _lb = lds[BUF] + wv * 4096; \
    __builtin_amdgcn_global_load_lds((__attribute__((address_space(1))) void*)(gp),        (__attribute__((address_space(3))) void*)(_lb),        16, 0, 0); \
    __builtin_amdgcn_global_load_lds((__attribute__((address_space(1))) void*)(gp + 1024), (__attribute__((address_space(3))) void*)(_lb + 1024), 16, 0, 0); \
    __builtin_amdgcn_global_load_lds((__attribute__((address_space(1))) void*)(gp + 2048), (__attribute__((address_space(3))) void*)(_lb + 2048), 16, 0, 0); \
    __builtin_amdgcn_global_load_lds((__attribute__((address_space(1))) void*)(gp + 3072), (__attribute__((address_space(3))) void*)(_lb + 3072), 16, 0, 0); \
  } while (0)

  float lsum = 0.f;
  f32x4 oacc[4];
#pragma unroll
  for (int dt = 0; dt < 4; ++dt) oacc[dt] = (f32x4){0.f, 0.f, 0.f, 0.f};

  STAGE(0);
  gp += gstride;
  __syncthreads();  // compiler drains vmcnt before barrier -> tile 0 ready

  int cur = 0;
  for (int kt = 0; kt < NKT; ++kt) {
    if (kt + 1 < NKT) { STAGE(cur ^ 1); gp += gstride; }  // prefetch next

    float4v kn2v[4];
#pragma unroll
    for (int nt = 0; nt < 4; ++nt)
      kn2v[nt] = *(const float4v*)(ktail + nt * 64 + gg * 16);
    ktail += KTILE;

    const char* ksc = lds[cur];
    const char* vsc = lds[cur] + 8192;

    // ---- QK^T swapped: dacc[nt][r] = kC*dot for s_loc=nt*16+4gg+r, q=16wv+cl
    f32x4 dacc[4];
#pragma unroll
    for (int nt = 0; nt < 4; ++nt) {
      bf16x8 ka0 = *(const bf16x8*)(ksc + swz((nt * 16 + cl) * 128 + gg * 16));
      bf16x8 ka1 = *(const bf16x8*)(ksc + swz((nt * 16 + cl) * 128 + gg * 16 + 64));
      f32x4 acc = {0.f, 0.f, 0.f, 0.f};
      acc = __builtin_amdgcn_mfma_f32_16x16x32_bf16(ka0, qb0.v, acc, 0, 0, 0);
      acc = __builtin_amdgcn_mfma_f32_16x16x32_bf16(ka1, qb1.v, acc, 0, 0, 0);
      dacc[nt] = acc;
    }

    // ---- scores: p = 2^sqrt(max(qn2*kn2 - dot^2, eps)); no max-subtraction
    // (s in [0, ~23] -> p in [1, 2^23]: f32/bf16 safe; softmax normalizes)
    float sc[4][4];
#pragma unroll
    for (int nt = 0; nt < 4; ++nt)
#pragma unroll
      for (int r = 0; r < 4; ++r) {
        const float dot = dacc[nt][r];
        float w2 = fmaf(-dot, dot, qn2 * kn2v[nt][r]);
        w2 = fmaxf(w2, kEpsC);
        const float p = __builtin_amdgcn_exp2f(__builtin_amdgcn_sqrtf(w2));
        sc[nt][r] = p;
        lsum += p;
      }

    // ---- P fragments lane-local (sigma baked into V); pack via cvt_pk ----
    frag pa0, pa1;
    pa0.w[0] = cvtpk(sc[0][0], sc[0][1]); pa0.w[1] = cvtpk(sc[0][2], sc[0][3]);
    pa0.w[2] = cvtpk(sc[1][0], sc[1][1]); pa0.w[3] = cvtpk(sc[1][2], sc[1][3]);
    pa1.w[0] = cvtpk(sc[2][0], sc[2][1]); pa1.w[1] = cvtpk(sc[2][2], sc[2][3]);
    pa1.w[2] = cvtpk(sc[3][0], sc[3][1]); pa1.w[3] = cvtpk(sc[3][2], sc[3][3]);

    // ---- PV ----
#pragma unroll
    for (int dt = 0; dt < 4; ++dt) {
      bf16x8 vb0 = *(const bf16x8*)(vsc + swz((dt * 16 + cl) * 128 + gg * 16));
      bf16x8 vb1 = *(const bf16x8*)(vsc + swz((dt * 16 + cl) * 128 + gg * 16 + 64));
      f32x4 acc = oacc[dt];
      acc = __builtin_amdgcn_mfma_f32_16x16x32_bf16(pa0.v, vb0, acc, 0, 0, 0);
      acc = __builtin_amdgcn_mfma_f32_16x16x32_bf16(pa1.v, vb1, acc, 0, 0, 0);
      oacc[dt] = acc;
    }

    __syncthreads();  // next tile's glls drained; buffers safe to swap
    cur ^= 1;
  }
#undef STAGE

  // ---- epilogue: deferred lsum reduce across gg, then normalize & store ----
  lsum += __shfl_xor(lsum, 16);
  lsum += __shfl_xor(lsum, 32);
  const float inv = 1.f / lsum;
  float inv4[4];
#pragma unroll
  for (int r = 0; r < 4; ++r)
    inv4[r] = __shfl(inv, (lane & 48) | (gg * 4 + r));
#pragma unroll
  for (int r = 0; r < 4; ++r) {
    const int l = l0 + wv * 16 + gg * 4 + r;
    float* op = Og + (((size_t)b * kL + l) * kH + h) * 64;
#pragma unroll
    for (int dt = 0; dt < 4; ++dt)
      op[dt * 16 + cl] = oacc[dt][r] * inv4[r];
  }
}

extern "C" void kernel_launch(void* const* d_in, const int* in_sizes, int n_in,
                              void* d_out, int out_size, void* d_ws, size_t ws_size,
                              hipStream_t stream) {
  const float* Qg = (const float*)d_in[0];
  const float* Kg = (const float*)d_in[1];
  const float* Vg = (const float*)d_in[2];
  float* Og = (float*)d_out;
  // ws: Kb tiled (32bh*32kt*8448B = 8.25MB) | Vt tiled (8MB) -> 16.25MB total
  char* Kb = (char*)d_ws;
  char* Vt = (char*)d_ws + (size_t)1024 * KTILE;
  prep_k<<<2048, 256, 0, stream>>>(Kg, Kb);
  prep_v<<<1024, 256, 0, stream>>>(Vg, Vt);
  dim3 grid(kL / QB, 32);
  geo_attn_kernel<<<grid, dim3(256), 0, stream>>>(Qg, Kb, Vt, Og);
}